// Round 1
// baseline (996.372 us; speedup 1.0000x reference)
//
#include <hip/hip_runtime.h>

// Problem dims (fixed by setup_inputs): b=4, h=8, L=256, d=64
#define L_SEQ 256
#define D_HEAD 64
#define MASK_VAL (-4294967295.0f)  // -2^32 + 1

// One block per (b,h,q) row. 256 threads = 16 k-groups x 16 d-float4 lanes.
// Streams tmK row (64 KiB) for energy, tmV row (64 KiB) for output.
// K/V slabs (128 KiB per (b,h)) are reused by 256 blocks -> L2-resident.
__global__ __launch_bounds__(256) void ta_sdp_kernel(
    const float* __restrict__ Q, const float* __restrict__ K,
    const float* __restrict__ V, const float* __restrict__ tmK,
    const float* __restrict__ tmV, const float* __restrict__ amask,
    const unsigned char* __restrict__ pmask,
    float* __restrict__ O_out, float* __restrict__ W_out)
{
    const int row = blockIdx.x;          // row = bh*L + q
    const int q   = row & (L_SEQ - 1);
    const int bh  = row >> 8;            // [0, 32)
    const int b   = bh >> 3;             // h = 8

    const int t   = threadIdx.x;
    const int dd4 = t & 15;              // which float4 of the d=64 dim
    const int kg  = t >> 4;              // k-group [0,16)

    const float4* Q4  = (const float4*)(Q   + (size_t)row * D_HEAD);
    const float4* K4  = (const float4*)(K   + (size_t)bh * L_SEQ * D_HEAD);
    const float4* V4  = (const float4*)(V   + (size_t)bh * L_SEQ * D_HEAD);
    const float4* tK4 = (const float4*)(tmK + (size_t)row * L_SEQ * D_HEAD);
    const float4* tV4 = (const float4*)(tmV + (size_t)row * L_SEQ * D_HEAD);

    __shared__ float  s_e[L_SEQ];
    __shared__ float  s_red[8];
    __shared__ float4 s_acc[256];

    // Q fragment for this lane's float4 slice (L1/L2 broadcast, tiny)
    const float4 q4 = Q4[dd4];

    // ---- Phase 1: energy[k] = dot(tmK[q,k,:]+K[k,:], Q[q,:]) ----
    // Per iter: block reads 16 contiguous k's (4 KiB) from each of tmK, K.
#pragma unroll 4
    for (int k0 = 0; k0 < 16; ++k0) {
        const int k  = k0 * 16 + kg;
        const int i4 = k * (D_HEAD / 4) + dd4;
        const float4 a = tK4[i4];
        const float4 c = K4[i4];
        float p = (a.x + c.x) * q4.x + (a.y + c.y) * q4.y
                + (a.z + c.z) * q4.z + (a.w + c.w) * q4.w;
        p += __shfl_xor(p, 1);
        p += __shfl_xor(p, 2);
        p += __shfl_xor(p, 4);
        p += __shfl_xor(p, 8);
        if (dd4 == 0) s_e[k] = p;
    }
    __syncthreads();

    // ---- Phase 2: scale + masks + softmax over k (one element per thread) ----
    float e = s_e[t] * 0.125f + amask[q * L_SEQ + t];
    if (pmask[b * L_SEQ + t]) e = MASK_VAL;

    float m = e;
#pragma unroll
    for (int off = 32; off; off >>= 1) m = fmaxf(m, __shfl_xor(m, off));
    if ((t & 63) == 0) s_red[t >> 6] = m;
    __syncthreads();
    m = fmaxf(fmaxf(s_red[0], s_red[1]), fmaxf(s_red[2], s_red[3]));

    const float p = __expf(e - m);
    float s = p;
#pragma unroll
    for (int off = 32; off; off >>= 1) s += __shfl_xor(s, off);
    if ((t & 63) == 0) s_red[4 + (t >> 6)] = s;
    __syncthreads();
    s = (s_red[4] + s_red[5]) + (s_red[6] + s_red[7]);

    const float w = p / s;
    W_out[(size_t)row * L_SEQ + t] = w;   // coalesced attention_weight store
    s_e[t] = w;
    __syncthreads();

    // ---- Phase 3: O[q,:] = sum_k w[k] * (V[k,:] + tmV[q,k,:]) ----
    float4 acc = make_float4(0.f, 0.f, 0.f, 0.f);
#pragma unroll 4
    for (int k0 = 0; k0 < 16; ++k0) {
        const int k  = k0 * 16 + kg;
        const float wk = s_e[k];          // LDS broadcast within 16-lane group
        const int i4 = k * (D_HEAD / 4) + dd4;
        const float4 a = tV4[i4];
        const float4 c = V4[i4];
        acc.x += wk * (a.x + c.x);
        acc.y += wk * (a.y + c.y);
        acc.z += wk * (a.z + c.z);
        acc.w += wk * (a.w + c.w);
    }
    s_acc[t] = acc;
    __syncthreads();

    // Tree-reduce over the 16 k-groups (layout: t = kg*16 + dd4)
#pragma unroll
    for (int s2 = 8; s2 > 0; s2 >>= 1) {
        if (kg < s2) {
            const float4 o = s_acc[t + s2 * 16];
            acc.x += o.x; acc.y += o.y; acc.z += o.z; acc.w += o.w;
            s_acc[t] = acc;
        }
        __syncthreads();
    }
    if (kg == 0) {
        ((float4*)(O_out + (size_t)row * D_HEAD))[dd4] = acc;
    }
}

extern "C" void kernel_launch(void* const* d_in, const int* in_sizes, int n_in,
                              void* d_out, int out_size, void* d_ws, size_t ws_size,
                              hipStream_t stream) {
    const float*         Q     = (const float*)d_in[0];
    const float*         K     = (const float*)d_in[1];
    const float*         V     = (const float*)d_in[2];
    const float*         tmK   = (const float*)d_in[3];
    const float*         tmV   = (const float*)d_in[4];
    const float*         amask = (const float*)d_in[5];
    const unsigned char* pmask = (const unsigned char*)d_in[6];

    float* O_out = (float*)d_out;
    float* W_out = (float*)d_out + in_sizes[0];  // O has b*h*L*d = in_sizes[0] elems

    const int rows = 4 * 8 * L_SEQ;  // b*h*L = 8192 blocks
    ta_sdp_kernel<<<dim3(rows), dim3(256), 0, stream>>>(
        Q, K, V, tmK, tmV, amask, pmask, O_out, W_out);
}

// Round 2
// 987.034 us; speedup vs baseline: 1.0095x; 1.0095x over previous
//
#include <hip/hip_runtime.h>

// Problem dims (fixed by setup_inputs): b=4, h=8, L=256, d=64
#define L_SEQ 256
#define D_HEAD 64
#define MASK_VAL (-4294967295.0f)  // -2^32 + 1

// ---------------------------------------------------------------------------
// Kernel A: energy = (Q.K^T + einsum(tmK,Q)) / 8  + masks ; softmax -> W
// One block per (b,h,q) row; 256 threads = 16 k-groups x 16 d-float4 lanes.
// Hot loop is pure VMEM + FMA + one ds_write (no shuffle chains).
// ---------------------------------------------------------------------------
__global__ __launch_bounds__(256) void ta_energy_softmax(
    const float* __restrict__ Q, const float* __restrict__ K,
    const float* __restrict__ tmK, const float* __restrict__ amask,
    const unsigned char* __restrict__ pmask, float* __restrict__ W_out)
{
    const int row = blockIdx.x;          // row = bh*L + q
    const int q   = row & (L_SEQ - 1);
    const int bh  = row >> 8;
    const int b   = bh >> 3;             // h = 8

    const int t   = threadIdx.x;
    const int dd4 = t & 15;              // float4 index within d=64
    const int kg  = t >> 4;              // k-group [0,16)

    __shared__ float s_part[L_SEQ][17];  // +1 pad: reduce reads are 2-way (free)
    __shared__ float s_red[8];

    const float4* Q4  = (const float4*)(Q   + (size_t)row * D_HEAD);
    const float4* K4  = (const float4*)(K   + (size_t)bh * L_SEQ * D_HEAD);
    const float4* tK4 = (const float4*)(tmK + (size_t)row * L_SEQ * D_HEAD);

    const float4 q4 = Q4[dd4];

    // Stream tmK row (64 KiB) + K slab (L2-resident). Per iter the block
    // touches 16 contiguous k's (4 KiB per array) -> fully coalesced.
#pragma unroll 8
    for (int k0 = 0; k0 < 16; ++k0) {
        const int k  = k0 * 16 + kg;
        const int i4 = k * (D_HEAD / 4) + dd4;
        const float4 a = tK4[i4];
        const float4 c = K4[i4];
        float p = (a.x + c.x) * q4.x + (a.y + c.y) * q4.y
                + (a.z + c.z) * q4.z + (a.w + c.w) * q4.w;
        s_part[k][dd4] = p;
    }
    __syncthreads();

    // Thread t owns k = t: reduce the 16 partials (2-way bank alias, free).
    float e = 0.f;
#pragma unroll
    for (int j = 0; j < 16; ++j) e += s_part[t][j];
    e = e * 0.125f + amask[q * L_SEQ + t];
    if (pmask[b * L_SEQ + t]) e = MASK_VAL;

    // Block softmax over 256 elements (4 waves).
    float m = e;
#pragma unroll
    for (int off = 32; off; off >>= 1) m = fmaxf(m, __shfl_xor(m, off));
    if ((t & 63) == 0) s_red[t >> 6] = m;
    __syncthreads();
    m = fmaxf(fmaxf(s_red[0], s_red[1]), fmaxf(s_red[2], s_red[3]));

    const float p = __expf(e - m);
    float s = p;
#pragma unroll
    for (int off = 32; off; off >>= 1) s += __shfl_xor(s, off);
    if ((t & 63) == 0) s_red[4 + (t >> 6)] = s;
    __syncthreads();
    s = (s_red[4] + s_red[5]) + (s_red[6] + s_red[7]);

    W_out[(size_t)row * L_SEQ + t] = p / s;
}

// ---------------------------------------------------------------------------
// Kernel B: O[q,:] = sum_k W[q,k] * (V[k,:] + tmV[q,k,:])
// w values live in registers; hot loop = 2 loads + 8 VALU, zero DS ops.
// ---------------------------------------------------------------------------
__global__ __launch_bounds__(256) void ta_output(
    const float* __restrict__ V, const float* __restrict__ tmV,
    const float* __restrict__ W, float* __restrict__ O_out)
{
    const int row = blockIdx.x;
    const int bh  = row >> 8;
    const int t   = threadIdx.x;
    const int dd4 = t & 15;
    const int kg  = t >> 4;

    __shared__ float  s_w[L_SEQ];
    __shared__ float4 s_acc[256];

    s_w[t] = W[(size_t)row * L_SEQ + t];
    __syncthreads();

    float wreg[16];
#pragma unroll
    for (int k0 = 0; k0 < 16; ++k0) wreg[k0] = s_w[k0 * 16 + kg];

    const float4* V4  = (const float4*)(V   + (size_t)bh * L_SEQ * D_HEAD);
    const float4* tV4 = (const float4*)(tmV + (size_t)row * L_SEQ * D_HEAD);

    float4 acc = make_float4(0.f, 0.f, 0.f, 0.f);
#pragma unroll 8
    for (int k0 = 0; k0 < 16; ++k0) {
        const int k  = k0 * 16 + kg;
        const int i4 = k * (D_HEAD / 4) + dd4;
        const float4 a = tV4[i4];
        const float4 c = V4[i4];
        const float wk = wreg[k0];
        acc.x += wk * (a.x + c.x);
        acc.y += wk * (a.y + c.y);
        acc.z += wk * (a.z + c.z);
        acc.w += wk * (a.w + c.w);
    }
    s_acc[t] = acc;
    __syncthreads();

    // Reduce 16 k-groups -> 1 in two LDS steps (layout: t = kg*16 + dd4).
    if (t < 64) {
        float4 r = s_acc[t];
        const float4 r1 = s_acc[t + 64];
        const float4 r2 = s_acc[t + 128];
        const float4 r3 = s_acc[t + 192];
        r.x += r1.x + r2.x + r3.x;
        r.y += r1.y + r2.y + r3.y;
        r.z += r1.z + r2.z + r3.z;
        r.w += r1.w + r2.w + r3.w;
        s_acc[t] = r;
    }
    __syncthreads();
    if (t < 16) {
        float4 r = s_acc[t];
        const float4 r1 = s_acc[t + 16];
        const float4 r2 = s_acc[t + 32];
        const float4 r3 = s_acc[t + 48];
        r.x += r1.x + r2.x + r3.x;
        r.y += r1.y + r2.y + r3.y;
        r.z += r1.z + r2.z + r3.z;
        r.w += r1.w + r2.w + r3.w;
        ((float4*)(O_out + (size_t)row * D_HEAD))[t] = r;
    }
}

extern "C" void kernel_launch(void* const* d_in, const int* in_sizes, int n_in,
                              void* d_out, int out_size, void* d_ws, size_t ws_size,
                              hipStream_t stream) {
    const float*         Q     = (const float*)d_in[0];
    const float*         K     = (const float*)d_in[1];
    const float*         V     = (const float*)d_in[2];
    const float*         tmK   = (const float*)d_in[3];
    const float*         tmV   = (const float*)d_in[4];
    const float*         amask = (const float*)d_in[5];
    const unsigned char* pmask = (const unsigned char*)d_in[6];

    float* O_out = (float*)d_out;
    float* W_out = (float*)d_out + in_sizes[0];  // O is b*h*L*d = in_sizes[0] elems

    const int rows = 4 * 8 * L_SEQ;  // b*h*L = 8192 blocks
    ta_energy_softmax<<<dim3(rows), dim3(256), 0, stream>>>(
        Q, K, tmK, amask, pmask, W_out);
    ta_output<<<dim3(rows), dim3(256), 0, stream>>>(
        V, tmV, W_out, O_out);
}